// Round 7
// baseline (536.896 us; speedup 1.0000x reference)
//
#include <hip/hip_runtime.h>
#include <hip/hip_bf16.h>

#define N_NODES 30000
#define F_INLEN 500
#define HID 16
#define OUTC 3
#define NEDGE 960000
#define EPB (NEDGE / N_NODES)   // 32 edges per conv block
#define YPITCH 20               // shorts per row: 40B -> conflict-free, 8B aligned
#define NB 1024                 // persistent blocks for gcn_mega (4 per CU guaranteed)
#define NPB 30                  // nodes per block: 1024*30 = 30720 >= 30000
#define EPBM 938                // edges per mega block: 1024*938 = 960512 >= NEDGE
#define GRP 64                  // barrier groups
#define GRPSZ (NB / GRP)        // 16 blocks per group

typedef float  f32x4 __attribute__((ext_vector_type(4)));
typedef float  f32x2 __attribute__((ext_vector_type(2)));
typedef short  s16x8 __attribute__((ext_vector_type(8)));

static __device__ __forceinline__ unsigned short f2bf(float f) {
    unsigned int u = __float_as_uint(f);
    unsigned int r = (u + 0x7fffu + ((u >> 16) & 1u)) >> 16;
    return (unsigned short)r;
}
static __device__ __forceinline__ unsigned int pack_bf16x2(float v0, float v1) {
#if __has_builtin(__builtin_amdgcn_cvt_pk_bf16_f32)
    typedef __bf16 bf16x2_t __attribute__((ext_vector_type(2)));
    union { bf16x2_t v; unsigned int u; } cv;
    cv.v = __builtin_amdgcn_cvt_pk_bf16_f32(v0, v1);
    return cv.u;
#else
    return (unsigned int)f2bf(v0) | (((unsigned int)f2bf(v1)) << 16);
#endif
}

// ---------------- K0: B-fragments + zero degi + zero barrier counters --------
__global__ void setup_kernel(const float* __restrict__ w2, short* __restrict__ bfragsG,
                             int* __restrict__ degi, int* __restrict__ gcnt,
                             int* __restrict__ groot)
{
    const int tid = threadIdx.x;
    const int gid = blockIdx.x * 256 + tid;
    if (gid < N_NODES) degi[gid] = 0;
    const int z = gid - N_NODES;
    if (z >= 0 && z < 4096) gcnt[z] = 0;
    if (z >= 4096 && z < 4160) groot[z - 4096] = 0;
    if (blockIdx.x == 0 && tid < 64) {
        const int n16 = tid & 15, q = tid >> 4;
#pragma unroll
        for (int j = 0; j < 8; j++) {
            {   // s = 0
                const int c = q * 8 + j;
                const int t = c >> 4, i = c & 15;
                bfragsG[tid * 16 + j] = (short)f2bf(w2[n16 * 48 + i * 3 + t]);
            }
            {   // s = 1 (zero for c >= 48)
                const int c = 32 + q * 8 + j;
                short v = 0;
                if (c < 48) { const int t = c >> 4, i = c & 15; v = (short)f2bf(w2[n16 * 48 + i * 3 + t]); }
                bfragsG[tid * 16 + 8 + j] = v;
            }
        }
    }
}

// ---------------- K1: conv (unchanged from R5, proven ~107 us) ---------------
__global__ __launch_bounds__(256, 7) void conv_fused(
    const float* __restrict__ x,
    const float* __restrict__ w1, const float* __restrict__ b1,
    const float* __restrict__ b2, const short* __restrict__ bfragsG,
    const int* __restrict__ dst, int* __restrict__ degi,
    float* __restrict__ h0)
{
    __shared__ __align__(16) float xp[502];
    __shared__ __align__(16) unsigned short yh[516 * YPITCH];
    __shared__ float red[64];

    const int tid  = threadIdx.x;
    const int node = blockIdx.x;
    const int lane = tid & 63;
    const int wave = tid >> 6;
    const int n16  = lane & 15;
    const int q    = lane >> 4;

    if (tid < EPB) {
        const int e = node * EPB + tid;
        atomicAdd(&degi[dst[e]], 1);
    }

    if (tid == 0) { xp[0] = 0.f; xp[501] = 0.f; }
    if (tid < 125) {
        const float4 v = ((const float4*)(x + (long long)node * F_INLEN))[tid];
        xp[4 * tid + 1] = v.x; xp[4 * tid + 2] = v.y;
        xp[4 * tid + 3] = v.z; xp[4 * tid + 4] = v.w;
    }
    {
        const int ri = tid >> 4;
        const int row = (ri == 0) ? 0 : (500 + ri);
        yh[row * YPITCH + (tid & 15)] = 0;
    }
    const s16x8* bfp = (const s16x8*)(bfragsG + lane * 16);
    const s16x8 bh0 = bfp[0], bh1 = bfp[1];

    f32x2 wt0[8], wt1[8], wt2[8], bb[8];
#pragma unroll
    for (int cp = 0; cp < 8; cp++) {
        const int c0 = 2 * cp, c1 = 2 * cp + 1;
        wt0[cp] = (f32x2){w1[c0 * 3 + 0], w1[c1 * 3 + 0]};
        wt1[cp] = (f32x2){w1[c0 * 3 + 1], w1[c1 * 3 + 1]};
        wt2[cp] = (f32x2){w1[c0 * 3 + 2], w1[c1 * 3 + 2]};
        bb[cp]  = (f32x2){b1[c0], b1[c1]};
    }
    __syncthreads();

    for (int p = tid; p < 500; p += 256) {
        const float x0 = xp[p], x1 = xp[p + 1], x2 = xp[p + 2];
        const f32x2 xv0 = {x0, x0}, xv1 = {x1, x1}, xv2 = {x2, x2};
        const f32x2 zero = {0.f, 0.f};
        unsigned int hp[8];
#pragma unroll
        for (int cp = 0; cp < 8; cp++) {
            f32x2 a = bb[cp];
            a = __builtin_elementwise_fma(wt0[cp], xv0, a);
            a = __builtin_elementwise_fma(wt1[cp], xv1, a);
            a = __builtin_elementwise_fma(wt2[cp], xv2, a);
            a = __builtin_elementwise_max(a, zero);
            hp[cp] = pack_bf16x2(a[0], a[1]);
        }
        uint2* d = (uint2*)&yh[(p + 1) * YPITCH];
        d[0] = make_uint2(hp[0], hp[1]);
        d[1] = make_uint2(hp[2], hp[3]);
        d[2] = make_uint2(hp[4], hp[5]);
        d[3] = make_uint2(hp[6], hp[7]);
    }
    __syncthreads();

    struct S8 { short4 lo, hi; };
    float mx0 = -3.0e38f, mx1 = -3.0e38f, mx2 = -3.0e38f, mx3 = -3.0e38f;
#pragma unroll
    for (int it = 0; it < 8; it++) {
        const int tile = wave * 8 + it;
        const int p0 = tile * 16 + n16;
        const int cA = (q & 1) * 8;
        const int rA = p0 + (q >> 1);
        const int rB = p0 + 2 + (q >> 1);
        S8 t0, t1;
        t0.lo = *(const short4*)&yh[rA * YPITCH + cA];
        t0.hi = *(const short4*)&yh[rA * YPITCH + cA + 4];
        t1.lo = *(const short4*)&yh[rB * YPITCH + cA];
        t1.hi = *(const short4*)&yh[rB * YPITCH + cA + 4];
        const s16x8 ah0 = *(const s16x8*)&t0;
        const s16x8 ah1 = *(const s16x8*)&t1;
        f32x4 acc = {0.f, 0.f, 0.f, 0.f};
        acc = __builtin_amdgcn_mfma_f32_16x16x32_bf16(ah0, bh0, acc, 0, 0, 0);
        acc = __builtin_amdgcn_mfma_f32_16x16x32_bf16(ah1, bh1, acc, 0, 0, 0);
        const int rb = tile * 16 + q * 4;
        if (rb + 0 < 500) mx0 = fmaxf(mx0, acc[0]);
        if (rb + 1 < 500) mx1 = fmaxf(mx1, acc[1]);
        if (rb + 2 < 500) mx2 = fmaxf(mx2, acc[2]);
        if (rb + 3 < 500) mx3 = fmaxf(mx3, acc[3]);
    }
    float m = fmaxf(fmaxf(mx0, mx1), fmaxf(mx2, mx3));
    m = fmaxf(m, __shfl_xor(m, 16));
    m = fmaxf(m, __shfl_xor(m, 32));
    if (lane < 16) red[wave * 16 + lane] = m;
    __syncthreads();
    if (tid < 16) {
        const float mm = fmaxf(fmaxf(red[tid], red[16 + tid]), fmaxf(red[32 + tid], red[48 + tid]));
        h0[node * HID + tid] = fmaxf(mm + b2[tid], 0.f);
    }
}

// ---------------- two-level grid barrier (64 groups of 16 blocks) ------------
static __device__ __forceinline__ void gridbar(int* __restrict__ gcnt,
                                               int* __restrict__ groot,
                                               int idx, int b)
{
    __syncthreads();
    if (threadIdx.x == 0) {
        const int grp = b & 63;
        const int old = __hip_atomic_fetch_add(&gcnt[idx * 1024 + grp * 16], 1,
                                               __ATOMIC_ACQ_REL, __HIP_MEMORY_SCOPE_AGENT);
        if (old == GRPSZ - 1)
            __hip_atomic_fetch_add(&groot[idx * 16], 1,
                                   __ATOMIC_ACQ_REL, __HIP_MEMORY_SCOPE_AGENT);
        while (__hip_atomic_load(&groot[idx * 16], __ATOMIC_ACQUIRE,
                                 __HIP_MEMORY_SCOPE_AGENT) < GRP)
            __builtin_amdgcn_s_sleep(32);
    }
    __syncthreads();
}

// ---------------- K2: fused GCN: scan -> CSR -> gather1 -> gather2 -----------
__global__ __launch_bounds__(256, 4) void gcn_mega(
    const int* __restrict__ src, const int* __restrict__ dst,
    const int* __restrict__ degi, const float* __restrict__ h0,
    float* __restrict__ h0p,
    int* __restrict__ rowptr, int* __restrict__ fill, int* __restrict__ srcb,
    const float* __restrict__ W1, const float* __restrict__ b1g,
    const float* __restrict__ W2, const float* __restrict__ b2g,
    float* __restrict__ t2p4, float* __restrict__ out,
    int* __restrict__ gsum, int* __restrict__ gcnt, int* __restrict__ groot)
{
    __shared__ float w1s[256];
    __shared__ float w2s[48];
    __shared__ float b1s[16];
    __shared__ float dinvS[NPB];

    const int tid  = threadIdx.x;
    const int b    = blockIdx.x;
    const int lane = tid & 63;
    const int wave = tid >> 6;
    const int base = b * NPB;
    int cnt = N_NODES - base;
    cnt = (cnt < 0) ? 0 : ((cnt > NPB) ? NPB : cnt);

    w1s[tid] = W1[tid];
    if (tid < 48) w2s[tid] = W2[tid];
    if (tid < 16) b1s[tid] = b1g[tid];

    // ---- A: block-local degree scan (wave 0) ----
    int dg = 0, incl = 0;
    if (wave == 0) {
        dg = (lane < cnt) ? degi[base + lane] : 0;
        incl = dg;
#pragma unroll
        for (int off = 1; off < 64; off <<= 1) {
            const int y = __shfl_up(incl, off);
            if (lane >= off) incl += y;
        }
        if (lane == 63) gsum[b] = incl;
    }
    gridbar(gcnt, groot, 0, b);

    // ---- B: global prefix; rowptr/fill/dinv; h0p prescale ----
    if (wave == 0) {
        int v[16];
        int loc = 0;
#pragma unroll
        for (int j = 0; j < 16; j++) { v[j] = gsum[lane * 16 + j]; loc += v[j]; }
        int incg = loc;
#pragma unroll
        for (int off = 1; off < 64; off <<= 1) {
            const int y = __shfl_up(incg, off);
            if (lane >= off) incg += y;
        }
        int cand = incg - loc;
        const int bo = b & 15;
#pragma unroll
        for (int j = 0; j < 16; j++) if (j < bo) cand += v[j];
        const int blockOff = __shfl(cand, b >> 4);
        if (lane < cnt) {
            const int n = base + lane;
            const int r = blockOff + (incl - dg);
            rowptr[n] = r;
            fill[n]   = r;
            dinvS[lane] = rsqrtf((float)(dg + 1));
        }
        if (b == 0 && lane == 0) rowptr[N_NODES] = NEDGE;
    }
    __syncthreads();
    for (int idx = tid; idx < cnt * HID; idx += 256) {
        const int ln = idx >> 4;
        const int g = (base + ln) * HID + (idx & 15);
        h0p[g] = h0[g] * dinvS[ln];
    }
    gridbar(gcnt, groot, 1, b);

    // ---- C: CSR bucket (938 edges per block) ----
    {
        const int e0 = b * EPBM;
        int e1 = e0 + EPBM; if (e1 > NEDGE) e1 = NEDGE;
        for (int e = e0 + tid; e < e1; e += 256) {
            const int d = dst[e];
            const int pos = atomicAdd(&fill[d], 1);
            srcb[pos] = src[e];
        }
    }
    gridbar(gcnt, groot, 2, b);

    // ---- D: gather1 + W1 + relu + W2 -> t2p4 ----
    {
        const int sub = tid & 15;
        const int e4  = sub >> 2;
        const int l4  = sub & 3;
#pragma unroll
        for (int r = 0; r < 2; r++) {
            const int ln = r * 16 + (tid >> 4);
            const int node = base + ln;
            if (ln < cnt) {
                const int beg = rowptr[node], end = rowptr[node + 1];
                f32x4 acc = {0.f, 0.f, 0.f, 0.f};
                if (e4 == 0) acc = *(const f32x4*)(h0p + node * HID + l4 * 4);
                for (int i = beg + e4; i < end; i += 4) {
                    const int s = srcb[i];
                    acc += *(const f32x4*)(h0p + s * HID + l4 * 4);
                }
#pragma unroll
                for (int c = 0; c < 4; c++) {
                    acc[c] += __shfl_xor(acc[c], 4);
                    acc[c] += __shfl_xor(acc[c], 8);
                }
                const int tb = (tid & 63) & ~3;
                float y = 0.f;
#pragma unroll
                for (int i = 0; i < 16; i++) {
                    const float a = __shfl(acc[i & 3], tb | (i >> 2));
                    y = fmaf(a, w1s[i * 16 + sub], y);
                }
                const float dv = dinvS[ln];
                const float h = fmaxf(b1s[sub] + dv * y, 0.f);
                float d0 = h * w2s[sub * 3 + 0];
                float d1 = h * w2s[sub * 3 + 1];
                float d2 = h * w2s[sub * 3 + 2];
#pragma unroll
                for (int msk = 1; msk < 16; msk <<= 1) {
                    d0 += __shfl_xor(d0, msk);
                    d1 += __shfl_xor(d1, msk);
                    d2 += __shfl_xor(d2, msk);
                }
                if (sub < 3) {
                    const float dval = (sub == 0) ? d0 : (sub == 1) ? d1 : d2;
                    t2p4[node * 4 + sub] = dval * dv;
                }
            }
        }
    }
    gridbar(gcnt, groot, 3, b);

    // ---- E: gather2 + bias + log_softmax ----
    {
        const int ln = tid >> 2;
        const int node = base + ln;
        if (ln < cnt) {
            const int l = tid & 3;
            const int beg = rowptr[node], end = rowptr[node + 1];
            f32x4 acc = {0.f, 0.f, 0.f, 0.f};
            if (l == 0) acc = *(const f32x4*)(t2p4 + node * 4);
            for (int i = beg + l; i < end; i += 4) {
                const int s = srcb[i];
                acc += *(const f32x4*)(t2p4 + s * 4);
            }
#pragma unroll
            for (int c = 0; c < 3; c++) {
                acc[c] += __shfl_xor(acc[c], 1);
                acc[c] += __shfl_xor(acc[c], 2);
            }
            const float dv = dinvS[ln];
            const float z0 = b2g[0] + dv * acc[0];
            const float z1 = b2g[1] + dv * acc[1];
            const float z2 = b2g[2] + dv * acc[2];
            const float m = fmaxf(z0, fmaxf(z1, z2));
            const float lg = m + logf(expf(z0 - m) + expf(z1 - m) + expf(z2 - m));
            if (l < 3) {
                const float z = (l == 0) ? z0 : (l == 1) ? z1 : z2;
                out[node * 3 + l] = z - lg;
            }
        }
    }
}

extern "C" void kernel_launch(void* const* d_in, const int* in_sizes, int n_in,
                              void* d_out, int out_size, void* d_ws, size_t ws_size,
                              hipStream_t stream)
{
    const float* x   = (const float*)d_in[0];
    const float* w1  = (const float*)d_in[1];
    const float* b1  = (const float*)d_in[2];
    const float* w2  = (const float*)d_in[3];
    const float* b2  = (const float*)d_in[4];
    const float* g1w = (const float*)d_in[5];
    const float* g1b = (const float*)d_in[6];
    const float* g2w = (const float*)d_in[7];
    const float* g2b = (const float*)d_in[8];
    const int*   ei  = (const int*)d_in[9];
    const int* src = ei;
    const int* dst = ei + NEDGE;

    float* ws      = (float*)d_ws;
    float* h0      = ws;                       // 480000 f (t2p4 aliases head)
    float* t2p4    = ws;                       // 120000 f
    float* h0p     = ws + 480000;              // 480000 f
    int*   rowptr  = (int*)(ws + 960000);      // 30001 i (+pad)
    int*   fill    = (int*)(ws + 990004);      // 30000 i
    int*   degi    = (int*)(ws + 1020004);     // 30000 i
    int*   srcb    = (int*)(ws + 1050004);     // 960000 i
    short* bfragsG = (short*)(ws + 2010004);   // 1024 s = 512 i (16B aligned)
    int*   gsum    = (int*)(ws + 2010516);     // 1024 i
    int*   gcnt    = (int*)(ws + 2011540);     // 4096 i
    int*   groot   = (int*)(ws + 2015636);     // 64 i
    float* out     = (float*)d_out;

    setup_kernel<<<134, 256, 0, stream>>>(w2, bfragsG, degi, gcnt, groot);
    conv_fused<<<N_NODES, 256, 0, stream>>>(x, w1, b1, b2, bfragsG, dst, degi, h0);
    gcn_mega<<<NB, 256, 0, stream>>>(src, dst, degi, h0, h0p,
                                     rowptr, fill, srcb,
                                     g1w, g1b, g2w, g2b, t2p4, out,
                                     gsum, gcnt, groot);
}

// Round 8
// 389.468 us; speedup vs baseline: 1.3785x; 1.3785x over previous
//
#include <hip/hip_runtime.h>
#include <hip/hip_bf16.h>

#define N_NODES 30000
#define F_INLEN 500
#define HID 16
#define OUTC 3
#define NEDGE 960000
#define EPB (NEDGE / N_NODES)   // 32 edges per conv block
#define YPITCH 20               // shorts per row: 40B -> conflict-free, 8B aligned
#define NBIN 938                // bins of 32 nodes: 938*32 = 30016 >= 30000
#define RBLK 256                // histogram/reorder blocks
#define EPRB (NEDGE / RBLK)     // 3750 edges per reorder block

typedef float  f32x4 __attribute__((ext_vector_type(4)));
typedef float  f32x2 __attribute__((ext_vector_type(2)));
typedef short  s16x8 __attribute__((ext_vector_type(8)));

static __device__ __forceinline__ unsigned short f2bf(float f) {
    unsigned int u = __float_as_uint(f);
    unsigned int r = (u + 0x7fffu + ((u >> 16) & 1u)) >> 16;
    return (unsigned short)r;
}
static __device__ __forceinline__ unsigned int pack_bf16x2(float v0, float v1) {
#if __has_builtin(__builtin_amdgcn_cvt_pk_bf16_f32)
    typedef __bf16 bf16x2_t __attribute__((ext_vector_type(2)));
    union { bf16x2_t v; unsigned int u; } cv;
    cv.v = __builtin_amdgcn_cvt_pk_bf16_f32(v0, v1);
    return cv.u;
#else
    return (unsigned int)f2bf(v0) | (((unsigned int)f2bf(v1)) << 16);
#endif
}

// ---------------- K0: B-fragments + zero degi --------------------------------
__global__ void setup_kernel(const float* __restrict__ w2, short* __restrict__ bfragsG,
                             int* __restrict__ degi)
{
    const int tid = threadIdx.x;
    const int gid = blockIdx.x * 256 + tid;
    if (gid < N_NODES) degi[gid] = 0;
    if (blockIdx.x == 0 && tid < 64) {
        const int n16 = tid & 15, q = tid >> 4;
#pragma unroll
        for (int j = 0; j < 8; j++) {
            {   // s = 0
                const int c = q * 8 + j;
                const int t = c >> 4, i = c & 15;
                bfragsG[tid * 16 + j] = (short)f2bf(w2[n16 * 48 + i * 3 + t]);
            }
            {   // s = 1 (zero for c >= 48)
                const int c = 32 + q * 8 + j;
                short v = 0;
                if (c < 48) { const int t = c >> 4, i = c & 15; v = (short)f2bf(w2[n16 * 48 + i * 3 + t]); }
                bfragsG[tid * 16 + 8 + j] = v;
            }
        }
    }
}

// ---------------- K1: conv (unchanged from R5, proven ~107 us) ---------------
__global__ __launch_bounds__(256, 7) void conv_fused(
    const float* __restrict__ x,
    const float* __restrict__ w1, const float* __restrict__ b1,
    const float* __restrict__ b2, const short* __restrict__ bfragsG,
    const int* __restrict__ dst, int* __restrict__ degi,
    float* __restrict__ h0)
{
    __shared__ __align__(16) float xp[502];
    __shared__ __align__(16) unsigned short yh[516 * YPITCH];
    __shared__ float red[64];

    const int tid  = threadIdx.x;
    const int node = blockIdx.x;
    const int lane = tid & 63;
    const int wave = tid >> 6;
    const int n16  = lane & 15;
    const int q    = lane >> 4;

    if (tid < EPB) {
        const int e = node * EPB + tid;
        atomicAdd(&degi[dst[e]], 1);
    }

    if (tid == 0) { xp[0] = 0.f; xp[501] = 0.f; }
    if (tid < 125) {
        const float4 v = ((const float4*)(x + (long long)node * F_INLEN))[tid];
        xp[4 * tid + 1] = v.x; xp[4 * tid + 2] = v.y;
        xp[4 * tid + 3] = v.z; xp[4 * tid + 4] = v.w;
    }
    {
        const int ri = tid >> 4;
        const int row = (ri == 0) ? 0 : (500 + ri);
        yh[row * YPITCH + (tid & 15)] = 0;
    }
    const s16x8* bfp = (const s16x8*)(bfragsG + lane * 16);
    const s16x8 bh0 = bfp[0], bh1 = bfp[1];

    f32x2 wt0[8], wt1[8], wt2[8], bb[8];
#pragma unroll
    for (int cp = 0; cp < 8; cp++) {
        const int c0 = 2 * cp, c1 = 2 * cp + 1;
        wt0[cp] = (f32x2){w1[c0 * 3 + 0], w1[c1 * 3 + 0]};
        wt1[cp] = (f32x2){w1[c0 * 3 + 1], w1[c1 * 3 + 1]};
        wt2[cp] = (f32x2){w1[c0 * 3 + 2], w1[c1 * 3 + 2]};
        bb[cp]  = (f32x2){b1[c0], b1[c1]};
    }
    __syncthreads();

    for (int p = tid; p < 500; p += 256) {
        const float x0 = xp[p], x1 = xp[p + 1], x2 = xp[p + 2];
        const f32x2 xv0 = {x0, x0}, xv1 = {x1, x1}, xv2 = {x2, x2};
        const f32x2 zero = {0.f, 0.f};
        unsigned int hp[8];
#pragma unroll
        for (int cp = 0; cp < 8; cp++) {
            f32x2 a = bb[cp];
            a = __builtin_elementwise_fma(wt0[cp], xv0, a);
            a = __builtin_elementwise_fma(wt1[cp], xv1, a);
            a = __builtin_elementwise_fma(wt2[cp], xv2, a);
            a = __builtin_elementwise_max(a, zero);
            hp[cp] = pack_bf16x2(a[0], a[1]);
        }
        uint2* d = (uint2*)&yh[(p + 1) * YPITCH];
        d[0] = make_uint2(hp[0], hp[1]);
        d[1] = make_uint2(hp[2], hp[3]);
        d[2] = make_uint2(hp[4], hp[5]);
        d[3] = make_uint2(hp[6], hp[7]);
    }
    __syncthreads();

    struct S8 { short4 lo, hi; };
    float mx0 = -3.0e38f, mx1 = -3.0e38f, mx2 = -3.0e38f, mx3 = -3.0e38f;
#pragma unroll
    for (int it = 0; it < 8; it++) {
        const int tile = wave * 8 + it;
        const int p0 = tile * 16 + n16;
        const int cA = (q & 1) * 8;
        const int rA = p0 + (q >> 1);
        const int rB = p0 + 2 + (q >> 1);
        S8 t0, t1;
        t0.lo = *(const short4*)&yh[rA * YPITCH + cA];
        t0.hi = *(const short4*)&yh[rA * YPITCH + cA + 4];
        t1.lo = *(const short4*)&yh[rB * YPITCH + cA];
        t1.hi = *(const short4*)&yh[rB * YPITCH + cA + 4];
        const s16x8 ah0 = *(const s16x8*)&t0;
        const s16x8 ah1 = *(const s16x8*)&t1;
        f32x4 acc = {0.f, 0.f, 0.f, 0.f};
        acc = __builtin_amdgcn_mfma_f32_16x16x32_bf16(ah0, bh0, acc, 0, 0, 0);
        acc = __builtin_amdgcn_mfma_f32_16x16x32_bf16(ah1, bh1, acc, 0, 0, 0);
        const int rb = tile * 16 + q * 4;
        if (rb + 0 < 500) mx0 = fmaxf(mx0, acc[0]);
        if (rb + 1 < 500) mx1 = fmaxf(mx1, acc[1]);
        if (rb + 2 < 500) mx2 = fmaxf(mx2, acc[2]);
        if (rb + 3 < 500) mx3 = fmaxf(mx3, acc[3]);
    }
    float m = fmaxf(fmaxf(mx0, mx1), fmaxf(mx2, mx3));
    m = fmaxf(m, __shfl_xor(m, 16));
    m = fmaxf(m, __shfl_xor(m, 32));
    if (lane < 16) red[wave * 16 + lane] = m;
    __syncthreads();
    if (tid < 16) {
        const float mm = fmaxf(fmaxf(red[tid], red[16 + tid]), fmaxf(red[32 + tid], red[48 + tid]));
        h0[node * HID + tid] = fmaxf(mm + b2[tid], 0.f);
    }
}

// ---------------- K2: per-block bin histogram (LDS, coalesced) ---------------
__global__ __launch_bounds__(256) void hist_kernel(const int* __restrict__ dst,
                                                   int* __restrict__ cntbase)
{
    __shared__ int h[NBIN];
    const int tid = threadIdx.x;
    const int blk = blockIdx.x;
    for (int i = tid; i < NBIN; i += 256) h[i] = 0;
    __syncthreads();
    const int e0 = blk * EPRB;
    for (int e = e0 + tid; e < e0 + EPRB; e += 256)
        atomicAdd(&h[dst[e] >> 5], 1);
    __syncthreads();
    for (int i = tid; i < NBIN; i += 256) cntbase[blk * NBIN + i] = h[i];
}

// ---------------- K3: scan (binstart + in-place block bases) + dinv ----------
__global__ __launch_bounds__(1024) void scan_kernel(
    int* __restrict__ cntbase, int* __restrict__ binstart,
    const int* __restrict__ degi, float* __restrict__ dinv)
{
    __shared__ int wtot[16];
    const int t = threadIdx.x;
    const int lane = t & 63, wv = t >> 6;
    int run = 0;
    if (t < NBIN) {
        for (int b = 0; b < RBLK; b++) {
            const int idx = b * NBIN + t;
            const int c = cntbase[idx];
            cntbase[idx] = run;       // local base (pre-binstart)
            run += c;
        }
    }
    // exclusive scan of per-bin totals over t
    int inc = run;
#pragma unroll
    for (int off = 1; off < 64; off <<= 1) {
        const int y = __shfl_up(inc, off);
        if (lane >= off) inc += y;
    }
    if (lane == 63) wtot[wv] = inc;
    __syncthreads();
    if (t == 0) {
        int r = 0;
#pragma unroll
        for (int w = 0; w < 16; w++) { const int tmp = wtot[w]; wtot[w] = r; r += tmp; }
    }
    __syncthreads();
    const int excl = wtot[wv] + inc - run;
    if (t < NBIN) {
        binstart[t] = excl;
        if (t == NBIN - 1) binstart[NBIN] = excl + run;
        for (int b = 0; b < RBLK; b++) cntbase[b * NBIN + t] += excl;
    }
    for (int i = t; i < N_NODES; i += 1024)
        dinv[i] = rsqrtf((float)(degi[i] + 1));
}

// ---------------- K4: reorder edges into bins (LDS-local offsets) + h0p ------
__global__ __launch_bounds__(256) void reorder_kernel(
    const int* __restrict__ src, const int* __restrict__ dst,
    const int* __restrict__ cntbase, int* __restrict__ packed,
    const float* __restrict__ h0, const float* __restrict__ dinv,
    float* __restrict__ h0p)
{
    const int tid = threadIdx.x;
    const int blk = blockIdx.x;
    if (blk < RBLK) {
        __shared__ int lfill[NBIN];
        __shared__ int lbase[NBIN];
        for (int i = tid; i < NBIN; i += 256) {
            lfill[i] = 0;
            lbase[i] = cntbase[blk * NBIN + i];
        }
        __syncthreads();
        const int e0 = blk * EPRB;
        for (int e = e0 + tid; e < e0 + EPRB; e += 256) {
            const int d = dst[e];
            const int bin = d >> 5;
            const int lofs = atomicAdd(&lfill[bin], 1);
            packed[lbase[bin] + lofs] = src[e] | ((d & 31) << 16);
        }
    } else {
        const int gid = (blk - RBLK) * 256 + tid;   // 480000 elements
        h0p[gid] = h0[gid] * dinv[gid >> 4];
    }
}

// ---------------- K5: binned aggregation layer 1 + W1 + relu + W2 ------------
// one block per bin (32 nodes); LDS f32 accumulator, pitch 17 (conflict-free)
__global__ __launch_bounds__(256) void agg1_kernel(
    const int* __restrict__ binstart, const int* __restrict__ packed,
    const float* __restrict__ h0p, const float* __restrict__ dinv,
    const float* __restrict__ W1, const float* __restrict__ b1g,
    const float* __restrict__ W2, float4* __restrict__ t2p4)
{
    __shared__ float w1s[256];
    __shared__ float w2s[48];
    __shared__ float b1s[16];
    __shared__ float accS[32 * 17];
    const int tid = threadIdx.x;
    const int blk = blockIdx.x;
    w1s[tid] = W1[tid];
    if (tid < 48) w2s[tid] = W2[tid];
    if (tid < 16) b1s[tid] = b1g[tid];
    for (int i = tid; i < 32 * 17; i += 256) accS[i] = 0.f;
    __syncthreads();

    const int beg = binstart[blk], end = binstart[blk + 1];
    const float4* h4 = (const float4*)h0p;
    const int q = tid & 3;
    for (int i = beg + (tid >> 2); i < end; i += 64) {
        const int p = packed[i];
        const int s = p & 0xFFFF;
        const int dl = p >> 16;
        const float4 v = h4[s * 4 + q];
        atomicAdd(&accS[dl * 17 + q * 4 + 0], v.x);
        atomicAdd(&accS[dl * 17 + q * 4 + 1], v.y);
        atomicAdd(&accS[dl * 17 + q * 4 + 2], v.z);
        atomicAdd(&accS[dl * 17 + q * 4 + 3], v.w);
    }
    __syncthreads();
    // add self-loop term (h0p[node])
    for (int idx = tid; idx < 32 * HID; idx += 256) {
        const int n = idx >> 4;
        const int node = blk * 32 + n;
        if (node < N_NODES) accS[n * 17 + (idx & 15)] += h0p[node * HID + (idx & 15)];
    }
    __syncthreads();
    if (tid < 128) {
        const int n = tid >> 2;
        const int node = blk * 32 + n;
        if (node < N_NODES) {
            const float dv = dinv[node];
            const int q2 = tid & 3;
            float y0 = 0.f, y1 = 0.f, y2 = 0.f, y3 = 0.f;
#pragma unroll
            for (int i = 0; i < 16; i++) {
                const float a = accS[n * 17 + i];
                y0 = fmaf(a, w1s[i * 16 + q2 * 4 + 0], y0);
                y1 = fmaf(a, w1s[i * 16 + q2 * 4 + 1], y1);
                y2 = fmaf(a, w1s[i * 16 + q2 * 4 + 2], y2);
                y3 = fmaf(a, w1s[i * 16 + q2 * 4 + 3], y3);
            }
            float d0 = 0.f, d1 = 0.f, d2 = 0.f;
            const float yv[4] = {y0, y1, y2, y3};
#pragma unroll
            for (int j = 0; j < 4; j++) {
                const int o = q2 * 4 + j;
                const float h = fmaxf(b1s[o] + dv * yv[j], 0.f);
                d0 = fmaf(h, w2s[o * 3 + 0], d0);
                d1 = fmaf(h, w2s[o * 3 + 1], d1);
                d2 = fmaf(h, w2s[o * 3 + 2], d2);
            }
            d0 += __shfl_xor(d0, 1); d0 += __shfl_xor(d0, 2);
            d1 += __shfl_xor(d1, 1); d1 += __shfl_xor(d1, 2);
            d2 += __shfl_xor(d2, 1); d2 += __shfl_xor(d2, 2);
            if (q2 == 0) t2p4[node] = make_float4(d0 * dv, d1 * dv, d2 * dv, 0.f);
        }
    }
}

// ---------------- K6: binned aggregation layer 2 + bias + log_softmax --------
__global__ __launch_bounds__(256) void agg2_kernel(
    const int* __restrict__ binstart, const int* __restrict__ packed,
    const float4* __restrict__ t2p4, const float* __restrict__ dinv,
    const float* __restrict__ b2g, float* __restrict__ out)
{
    __shared__ float acc2[32 * 5];
    const int tid = threadIdx.x;
    const int blk = blockIdx.x;
    for (int i = tid; i < 32 * 5; i += 256) acc2[i] = 0.f;
    __syncthreads();
    const int beg = binstart[blk], end = binstart[blk + 1];
    for (int i = beg + tid; i < end; i += 256) {
        const int p = packed[i];
        const int s = p & 0xFFFF;
        const int dl = p >> 16;
        const float4 v = t2p4[s];
        atomicAdd(&acc2[dl * 5 + 0], v.x);
        atomicAdd(&acc2[dl * 5 + 1], v.y);
        atomicAdd(&acc2[dl * 5 + 2], v.z);
    }
    __syncthreads();
    if (tid < 32) {
        const int node = blk * 32 + tid;
        if (node < N_NODES) {
            const float dv = dinv[node];
            const float4 self = t2p4[node];
            const float z0 = b2g[0] + dv * (acc2[tid * 5 + 0] + self.x);
            const float z1 = b2g[1] + dv * (acc2[tid * 5 + 1] + self.y);
            const float z2 = b2g[2] + dv * (acc2[tid * 5 + 2] + self.z);
            const float m = fmaxf(z0, fmaxf(z1, z2));
            const float lg = m + logf(expf(z0 - m) + expf(z1 - m) + expf(z2 - m));
            out[node * 3 + 0] = z0 - lg;
            out[node * 3 + 1] = z1 - lg;
            out[node * 3 + 2] = z2 - lg;
        }
    }
}

extern "C" void kernel_launch(void* const* d_in, const int* in_sizes, int n_in,
                              void* d_out, int out_size, void* d_ws, size_t ws_size,
                              hipStream_t stream)
{
    const float* x   = (const float*)d_in[0];
    const float* w1  = (const float*)d_in[1];
    const float* b1  = (const float*)d_in[2];
    const float* w2  = (const float*)d_in[3];
    const float* b2  = (const float*)d_in[4];
    const float* g1w = (const float*)d_in[5];
    const float* g1b = (const float*)d_in[6];
    const float* g2w = (const float*)d_in[7];
    const float* g2b = (const float*)d_in[8];
    const int*   ei  = (const int*)d_in[9];
    const int* src = ei;
    const int* dst = ei + NEDGE;

    float* ws      = (float*)d_ws;
    float*  h0      = ws;                      // 480000 f (dead after reorder tail)
    float4* t2p4    = (float4*)ws;             // 30000 float4 (aliases dead h0)
    float*  h0p     = ws + 480000;             // 480000 f
    float*  dinv    = ws + 960000;             // 30000 f
    int*    degi    = (int*)(ws + 990000);     // 30000 i
    int*    binstart= (int*)(ws + 1020000);    // 939 i (+pad to 1024)
    int*    cntbase = (int*)(ws + 1021024);    // 256*938 = 240128 i
    int*    packed  = (int*)(ws + 1261152);    // 960000 i
    short*  bfragsG = (short*)(ws + 2221152);  // 1024 s = 512 words
    float*  out     = (float*)d_out;

    setup_kernel<<<118, 256, 0, stream>>>(w2, bfragsG, degi);
    conv_fused<<<N_NODES, 256, 0, stream>>>(x, w1, b1, b2, bfragsG, dst, degi, h0);
    hist_kernel<<<RBLK, 256, 0, stream>>>(dst, cntbase);
    scan_kernel<<<1, 1024, 0, stream>>>(cntbase, binstart, degi, dinv);
    reorder_kernel<<<RBLK + (N_NODES * HID) / 256, 256, 0, stream>>>(
        src, dst, cntbase, packed, h0, dinv, h0p);
    agg1_kernel<<<NBIN, 256, 0, stream>>>(binstart, packed, h0p, dinv,
                                          g1w, g1b, g2w, t2p4);
    agg2_kernel<<<NBIN, 256, 0, stream>>>(binstart, packed, t2p4, dinv, g2b, out);
}

// Round 9
// 298.620 us; speedup vs baseline: 1.7979x; 1.3042x over previous
//
#include <hip/hip_runtime.h>
#include <hip/hip_bf16.h>

#define N_NODES 30000
#define F_INLEN 500
#define HID 16
#define OUTC 3
#define NEDGE 960000
#define EPB (NEDGE / N_NODES)   // 32 edges per conv block
#define YPITCH 20               // shorts per row: 40B -> conflict-free, 8B aligned
#define NBIN 938                // bins of 32 nodes: 938*32 = 30016 >= 30000
#define RBLK 64                 // reorder blocks
#define EPRB (NEDGE / RBLK)     // 15000 edges per reorder block
#define ECAP 1536               // per-bin edge capacity (mean 1024, sd 32)

typedef float  f32x4 __attribute__((ext_vector_type(4)));
typedef float  f32x2 __attribute__((ext_vector_type(2)));
typedef short  s16x8 __attribute__((ext_vector_type(8)));

static __device__ __forceinline__ unsigned short f2bf(float f) {
    unsigned int u = __float_as_uint(f);
    unsigned int r = (u + 0x7fffu + ((u >> 16) & 1u)) >> 16;
    return (unsigned short)r;
}
static __device__ __forceinline__ unsigned int pack_bf16x2(float v0, float v1) {
#if __has_builtin(__builtin_amdgcn_cvt_pk_bf16_f32)
    typedef __bf16 bf16x2_t __attribute__((ext_vector_type(2)));
    union { bf16x2_t v; unsigned int u; } cv;
    cv.v = __builtin_amdgcn_cvt_pk_bf16_f32(v0, v1);
    return cv.u;
#else
    return (unsigned int)f2bf(v0) | (((unsigned int)f2bf(v1)) << 16);
#endif
}

// ---------------- K0: B-fragments + zero degi + bin histogram ----------------
// 64 blocks x 512 threads; block b histograms edges [b*15000, (b+1)*15000)
__global__ __launch_bounds__(512) void setup_hist(
    const float* __restrict__ w2, short* __restrict__ bfragsG,
    int* __restrict__ degi, const int* __restrict__ dst, int* __restrict__ cntbase)
{
    __shared__ int h[NBIN];
    const int tid = threadIdx.x;
    const int blk = blockIdx.x;
    const int gid = blk * 512 + tid;
    if (gid < N_NODES) degi[gid] = 0;
    if (blk == 0 && tid < 64) {
        const int n16 = tid & 15, q = tid >> 4;
#pragma unroll
        for (int j = 0; j < 8; j++) {
            {   // s = 0
                const int c = q * 8 + j;
                const int t = c >> 4, i = c & 15;
                bfragsG[tid * 16 + j] = (short)f2bf(w2[n16 * 48 + i * 3 + t]);
            }
            {   // s = 1 (zero for c >= 48)
                const int c = 32 + q * 8 + j;
                short v = 0;
                if (c < 48) { const int t = c >> 4, i = c & 15; v = (short)f2bf(w2[n16 * 48 + i * 3 + t]); }
                bfragsG[tid * 16 + 8 + j] = v;
            }
        }
    }
    for (int i = tid; i < NBIN; i += 512) h[i] = 0;
    __syncthreads();
    const int e0 = blk * EPRB;
    for (int e = e0 + tid; e < e0 + EPRB; e += 512)
        atomicAdd(&h[dst[e] >> 5], 1);
    __syncthreads();
    for (int i = tid; i < NBIN; i += 512) cntbase[i * RBLK + blk] = h[i];
}

// ---------------- K1: conv (unchanged from R5, proven ~107 us) ---------------
__global__ __launch_bounds__(256, 7) void conv_fused(
    const float* __restrict__ x,
    const float* __restrict__ w1, const float* __restrict__ b1,
    const float* __restrict__ b2, const short* __restrict__ bfragsG,
    const int* __restrict__ dst, int* __restrict__ degi,
    float* __restrict__ h0)
{
    __shared__ __align__(16) float xp[502];
    __shared__ __align__(16) unsigned short yh[516 * YPITCH];
    __shared__ float red[64];

    const int tid  = threadIdx.x;
    const int node = blockIdx.x;
    const int lane = tid & 63;
    const int wave = tid >> 6;
    const int n16  = lane & 15;
    const int q    = lane >> 4;

    if (tid < EPB) {
        const int e = node * EPB + tid;
        atomicAdd(&degi[dst[e]], 1);
    }

    if (tid == 0) { xp[0] = 0.f; xp[501] = 0.f; }
    if (tid < 125) {
        const float4 v = ((const float4*)(x + (long long)node * F_INLEN))[tid];
        xp[4 * tid + 1] = v.x; xp[4 * tid + 2] = v.y;
        xp[4 * tid + 3] = v.z; xp[4 * tid + 4] = v.w;
    }
    {
        const int ri = tid >> 4;
        const int row = (ri == 0) ? 0 : (500 + ri);
        yh[row * YPITCH + (tid & 15)] = 0;
    }
    const s16x8* bfp = (const s16x8*)(bfragsG + lane * 16);
    const s16x8 bh0 = bfp[0], bh1 = bfp[1];

    f32x2 wt0[8], wt1[8], wt2[8], bb[8];
#pragma unroll
    for (int cp = 0; cp < 8; cp++) {
        const int c0 = 2 * cp, c1 = 2 * cp + 1;
        wt0[cp] = (f32x2){w1[c0 * 3 + 0], w1[c1 * 3 + 0]};
        wt1[cp] = (f32x2){w1[c0 * 3 + 1], w1[c1 * 3 + 1]};
        wt2[cp] = (f32x2){w1[c0 * 3 + 2], w1[c1 * 3 + 2]};
        bb[cp]  = (f32x2){b1[c0], b1[c1]};
    }
    __syncthreads();

    for (int p = tid; p < 500; p += 256) {
        const float x0 = xp[p], x1 = xp[p + 1], x2 = xp[p + 2];
        const f32x2 xv0 = {x0, x0}, xv1 = {x1, x1}, xv2 = {x2, x2};
        const f32x2 zero = {0.f, 0.f};
        unsigned int hp[8];
#pragma unroll
        for (int cp = 0; cp < 8; cp++) {
            f32x2 a = bb[cp];
            a = __builtin_elementwise_fma(wt0[cp], xv0, a);
            a = __builtin_elementwise_fma(wt1[cp], xv1, a);
            a = __builtin_elementwise_fma(wt2[cp], xv2, a);
            a = __builtin_elementwise_max(a, zero);
            hp[cp] = pack_bf16x2(a[0], a[1]);
        }
        uint2* d = (uint2*)&yh[(p + 1) * YPITCH];
        d[0] = make_uint2(hp[0], hp[1]);
        d[1] = make_uint2(hp[2], hp[3]);
        d[2] = make_uint2(hp[4], hp[5]);
        d[3] = make_uint2(hp[6], hp[7]);
    }
    __syncthreads();

    struct S8 { short4 lo, hi; };
    float mx0 = -3.0e38f, mx1 = -3.0e38f, mx2 = -3.0e38f, mx3 = -3.0e38f;
#pragma unroll
    for (int it = 0; it < 8; it++) {
        const int tile = wave * 8 + it;
        const int p0 = tile * 16 + n16;
        const int cA = (q & 1) * 8;
        const int rA = p0 + (q >> 1);
        const int rB = p0 + 2 + (q >> 1);
        S8 t0, t1;
        t0.lo = *(const short4*)&yh[rA * YPITCH + cA];
        t0.hi = *(const short4*)&yh[rA * YPITCH + cA + 4];
        t1.lo = *(const short4*)&yh[rB * YPITCH + cA];
        t1.hi = *(const short4*)&yh[rB * YPITCH + cA + 4];
        const s16x8 ah0 = *(const s16x8*)&t0;
        const s16x8 ah1 = *(const s16x8*)&t1;
        f32x4 acc = {0.f, 0.f, 0.f, 0.f};
        acc = __builtin_amdgcn_mfma_f32_16x16x32_bf16(ah0, bh0, acc, 0, 0, 0);
        acc = __builtin_amdgcn_mfma_f32_16x16x32_bf16(ah1, bh1, acc, 0, 0, 0);
        const int rb = tile * 16 + q * 4;
        if (rb + 0 < 500) mx0 = fmaxf(mx0, acc[0]);
        if (rb + 1 < 500) mx1 = fmaxf(mx1, acc[1]);
        if (rb + 2 < 500) mx2 = fmaxf(mx2, acc[2]);
        if (rb + 3 < 500) mx3 = fmaxf(mx3, acc[3]);
    }
    float m = fmaxf(fmaxf(mx0, mx1), fmaxf(mx2, mx3));
    m = fmaxf(m, __shfl_xor(m, 16));
    m = fmaxf(m, __shfl_xor(m, 32));
    if (lane < 16) red[wave * 16 + lane] = m;
    __syncthreads();
    if (tid < 16) {
        const float mm = fmaxf(fmaxf(red[tid], red[16 + tid]), fmaxf(red[32 + tid], red[48 + tid]));
        h0[node * HID + tid] = fmaxf(mm + b2[tid], 0.f);
    }
}

// ---------------- K2: scan: per-bin row prefix (int4) + binstart + dinv ------
__global__ __launch_bounds__(1024) void scan2_kernel(
    int* __restrict__ cntbase, int* __restrict__ binstart,
    const int* __restrict__ degi, float* __restrict__ dinv)
{
    __shared__ int wtot[16];
    const int t = threadIdx.x;
    const int lane = t & 63, wv = t >> 6;
    int4* row = (int4*)(cntbase + t * RBLK);
    int tot = 0;
    if (t < NBIN) {
#pragma unroll
        for (int k = 0; k < RBLK / 4; k++) {
            const int4 v = row[k];
            tot += v.x + v.y + v.z + v.w;
        }
    }
    int inc = tot;
#pragma unroll
    for (int off = 1; off < 64; off <<= 1) {
        const int y = __shfl_up(inc, off);
        if (lane >= off) inc += y;
    }
    if (lane == 63) wtot[wv] = inc;
    __syncthreads();
    if (t == 0) {
        int r = 0;
#pragma unroll
        for (int w = 0; w < 16; w++) { const int tmp = wtot[w]; wtot[w] = r; r += tmp; }
    }
    __syncthreads();
    const int excl = wtot[wv] + inc - tot;
    if (t < NBIN) {
        binstart[t] = excl;
        if (t == NBIN - 1) binstart[NBIN] = excl + tot;
        int run = excl;
#pragma unroll
        for (int k = 0; k < RBLK / 4; k++) {
            int4 v = row[k];
            int a;
            a = run; run += v.x; v.x = a;
            a = run; run += v.y; v.y = a;
            a = run; run += v.z; v.z = a;
            a = run; run += v.w; v.w = a;
            row[k] = v;
        }
    }
    for (int i = t; i < N_NODES; i += 1024)
        dinv[i] = rsqrtf((float)(degi[i] + 1));
}

// ---------------- K3: reorder with block-local LDS counting sort -------------
// 64 blocks x 512 thr, 15000 edges each; output writes are bin-sorted (runs ~16)
__global__ __launch_bounds__(512) void reorder_kernel(
    const int* __restrict__ src, const int* __restrict__ dst,
    const int* __restrict__ cntbase, int* __restrict__ packed)
{
    __shared__ int lbase[NBIN];
    __shared__ int lhist[NBIN];   // becomes scatter cursor (lofs)
    __shared__ int scA[NBIN];
    __shared__ int scB[NBIN];
    __shared__ int srt[EPRB];
    __shared__ unsigned short sbin[EPRB];
    const int tid = threadIdx.x;
    const int blk = blockIdx.x;
    for (int i = tid; i < NBIN; i += 512) {
        lhist[i] = 0;
        lbase[i] = cntbase[i * RBLK + blk];
    }
    __syncthreads();
    const int e0 = blk * EPRB;
    for (int e = e0 + tid; e < e0 + EPRB; e += 512)
        atomicAdd(&lhist[dst[e] >> 5], 1);
    __syncthreads();
    // inclusive Hillis-Steele over NBIN into pA
    for (int i = tid; i < NBIN; i += 512) scA[i] = lhist[i];
    __syncthreads();
    int* pA = scA; int* pB = scB;
    for (int off = 1; off < NBIN; off <<= 1) {
        for (int i = tid; i < NBIN; i += 512)
            pB[i] = pA[i] + ((i >= off) ? pA[i - off] : 0);
        __syncthreads();
        int* tp = pA; pA = pB; pB = tp;
    }
    // pA = inclusive; exclusive -> pB; cursor lhist := exclusive
    for (int i = tid; i < NBIN; i += 512) {
        const int ex = pA[i] - lhist[i];
        pB[i] = ex;
    }
    __syncthreads();
    for (int i = tid; i < NBIN; i += 512) lhist[i] = pB[i];
    __syncthreads();
    for (int e = e0 + tid; e < e0 + EPRB; e += 512) {
        const int d = dst[e];
        const int bin = d >> 5;
        const int pos = atomicAdd(&lhist[bin], 1);
        srt[pos] = src[e] | ((d & 31) << 16);
        sbin[pos] = (unsigned short)bin;
    }
    __syncthreads();
    for (int i = tid; i < EPRB; i += 512) {
        const int bin = sbin[i];
        packed[lbase[bin] + (i - pB[bin])] = srt[i];
    }
}

// ---------------- K4: agg layer 1: sort-by-dloc + register segmented sum -----
// one block per bin (32 nodes); 8 lanes/node = 2 edge-slots x 4 quads
__global__ __launch_bounds__(256) void agg1_kernel(
    const int* __restrict__ binstart, const int* __restrict__ packed,
    const float* __restrict__ h0, const float* __restrict__ dinv,
    const float* __restrict__ W1, const float* __restrict__ b1g,
    const float* __restrict__ W2, float4* __restrict__ t2p4)
{
    __shared__ float w1s[256];
    __shared__ float w2s[48];
    __shared__ float b1s[16];
    __shared__ float accS[32 * 17];
    __shared__ int eL[ECAP];
    __shared__ int srt[ECAP];
    __shared__ int h32[32], ls32[32], lofs32[32];
    const int tid = threadIdx.x;
    const int blk = blockIdx.x;
    w1s[tid] = W1[tid];
    if (tid < 48) w2s[tid] = W2[tid];
    if (tid < 16) b1s[tid] = b1g[tid];
    if (tid < 32) h32[tid] = 0;
    const int beg = binstart[blk];
    const int cnt = binstart[blk + 1] - beg;
    __syncthreads();
    for (int j = tid; j < cnt; j += 256) {
        const int p = packed[beg + j];
        eL[j] = p;
        atomicAdd(&h32[p >> 16], 1);
    }
    __syncthreads();
    if (tid < 32) {
        const int v = h32[tid];
        int inc = v;
#pragma unroll
        for (int off = 1; off < 32; off <<= 1) {
            const int y = __shfl_up(inc, off);
            if (tid >= off) inc += y;
        }
        ls32[tid] = inc - v;
        lofs32[tid] = inc - v;
    }
    __syncthreads();
    for (int j = tid; j < cnt; j += 256) {
        const int p = eL[j];
        const int pos = atomicAdd(&lofs32[p >> 16], 1);
        srt[pos] = p;
    }
    __syncthreads();
    // segmented accumulate: node n = tid>>3, eslot = (tid>>2)&1, quad q = tid&3
    const int n = tid >> 3;
    const int eslot = (tid >> 2) & 1;
    const int q = tid & 3;
    const int node = blk * 32 + n;
    const bool valid = node < N_NODES;
    f32x4 acc = {0.f, 0.f, 0.f, 0.f};
    if (valid) {
        const int s0 = ls32[n];
        const int s1 = s0 + h32[n];
        for (int i = s0 + eslot; i < s1; i += 2) {
            const int s = srt[i] & 0xFFFF;
            const f32x4 v = *(const f32x4*)(h0 + s * HID + q * 4);
            acc += v * dinv[s];
        }
    }
#pragma unroll
    for (int c = 0; c < 4; c++) acc[c] += __shfl_xor(acc[c], 4);
    if (valid && eslot == 0) {
        const f32x4 sf = *(const f32x4*)(h0 + node * HID + q * 4);
        acc += sf * dinv[node];
        accS[n * 17 + q * 4 + 0] = acc[0];
        accS[n * 17 + q * 4 + 1] = acc[1];
        accS[n * 17 + q * 4 + 2] = acc[2];
        accS[n * 17 + q * 4 + 3] = acc[3];
    }
    __syncthreads();
    if (tid < 128) {
        const int n2 = tid >> 2;
        const int node2 = blk * 32 + n2;
        if (node2 < N_NODES) {
            const float dv = dinv[node2];
            const int q2 = tid & 3;
            float y0 = 0.f, y1 = 0.f, y2 = 0.f, y3 = 0.f;
#pragma unroll
            for (int i = 0; i < 16; i++) {
                const float a = accS[n2 * 17 + i];
                y0 = fmaf(a, w1s[i * 16 + q2 * 4 + 0], y0);
                y1 = fmaf(a, w1s[i * 16 + q2 * 4 + 1], y1);
                y2 = fmaf(a, w1s[i * 16 + q2 * 4 + 2], y2);
                y3 = fmaf(a, w1s[i * 16 + q2 * 4 + 3], y3);
            }
            float d0 = 0.f, d1 = 0.f, d2 = 0.f;
            const float yv[4] = {y0, y1, y2, y3};
#pragma unroll
            for (int j = 0; j < 4; j++) {
                const int o = q2 * 4 + j;
                const float h = fmaxf(b1s[o] + dv * yv[j], 0.f);
                d0 = fmaf(h, w2s[o * 3 + 0], d0);
                d1 = fmaf(h, w2s[o * 3 + 1], d1);
                d2 = fmaf(h, w2s[o * 3 + 2], d2);
            }
            d0 += __shfl_xor(d0, 1); d0 += __shfl_xor(d0, 2);
            d1 += __shfl_xor(d1, 1); d1 += __shfl_xor(d1, 2);
            d2 += __shfl_xor(d2, 1); d2 += __shfl_xor(d2, 2);
            if (q2 == 0) t2p4[node2] = make_float4(d0 * dv, d1 * dv, d2 * dv, 0.f);
        }
    }
}

// ---------------- K5: agg layer 2 + bias + log_softmax -----------------------
// 8 edge-slot lanes per node
__global__ __launch_bounds__(256) void agg2_kernel(
    const int* __restrict__ binstart, const int* __restrict__ packed,
    const float4* __restrict__ t2p4, const float* __restrict__ dinv,
    const float* __restrict__ b2g, float* __restrict__ out)
{
    __shared__ int eL[ECAP];
    __shared__ int srt[ECAP];
    __shared__ int h32[32], ls32[32], lofs32[32];
    const int tid = threadIdx.x;
    const int blk = blockIdx.x;
    if (tid < 32) h32[tid] = 0;
    const int beg = binstart[blk];
    const int cnt = binstart[blk + 1] - beg;
    __syncthreads();
    for (int j = tid; j < cnt; j += 256) {
        const int p = packed[beg + j];
        eL[j] = p;
        atomicAdd(&h32[p >> 16], 1);
    }
    __syncthreads();
    if (tid < 32) {
        const int v = h32[tid];
        int inc = v;
#pragma unroll
        for (int off = 1; off < 32; off <<= 1) {
            const int y = __shfl_up(inc, off);
            if (tid >= off) inc += y;
        }
        ls32[tid] = inc - v;
        lofs32[tid] = inc - v;
    }
    __syncthreads();
    for (int j = tid; j < cnt; j += 256) {
        const int p = eL[j];
        const int pos = atomicAdd(&lofs32[p >> 16], 1);
        srt[pos] = p;
    }
    __syncthreads();
    const int n = tid >> 3;
    const int ln8 = tid & 7;
    const int node = blk * 32 + n;
    float a0 = 0.f, a1 = 0.f, a2 = 0.f;
    if (node < N_NODES) {
        const int s0 = ls32[n];
        const int s1 = s0 + h32[n];
        for (int i = s0 + ln8; i < s1; i += 8) {
            const int s = srt[i] & 0xFFFF;
            const float4 v = t2p4[s];
            a0 += v.x; a1 += v.y; a2 += v.z;
        }
    }
#pragma unroll
    for (int msk = 1; msk < 8; msk <<= 1) {
        a0 += __shfl_xor(a0, msk);
        a1 += __shfl_xor(a1, msk);
        a2 += __shfl_xor(a2, msk);
    }
    if (ln8 == 0 && node < N_NODES) {
        const float dv = dinv[node];
        const float4 self = t2p4[node];
        const float z0 = b2g[0] + dv * (a0 + self.x);
        const float z1 = b2g[1] + dv * (a1 + self.y);
        const float z2 = b2g[2] + dv * (a2 + self.z);
        const float m = fmaxf(z0, fmaxf(z1, z2));
        const float lg = m + logf(expf(z0 - m) + expf(z1 - m) + expf(z2 - m));
        out[node * 3 + 0] = z0 - lg;
        out[node * 3 + 1] = z1 - lg;
        out[node * 3 + 2] = z2 - lg;
    }
}

extern "C" void kernel_launch(void* const* d_in, const int* in_sizes, int n_in,
                              void* d_out, int out_size, void* d_ws, size_t ws_size,
                              hipStream_t stream)
{
    const float* x   = (const float*)d_in[0];
    const float* w1  = (const float*)d_in[1];
    const float* b1  = (const float*)d_in[2];
    const float* w2  = (const float*)d_in[3];
    const float* b2  = (const float*)d_in[4];
    const float* g1w = (const float*)d_in[5];
    const float* g1b = (const float*)d_in[6];
    const float* g2w = (const float*)d_in[7];
    const float* g2b = (const float*)d_in[8];
    const int*   ei  = (const int*)d_in[9];
    const int* src = ei;
    const int* dst = ei + NEDGE;

    float* ws = (float*)d_ws;
    float*  h0      = ws;                       // 480000 f
    float*  dinv    = ws + 480000;              // 30000 f
    float4* t2p4    = (float4*)(ws + 510000);   // 30000 float4 (16B aligned)
    int*    degi    = (int*)(ws + 630000);      // 30000 i
    int*    cntbase = (int*)(ws + 660000);      // 938*64 = 60032 i (16B aligned)
    int*    binstart= (int*)(ws + 720032);      // 939 (+pad 1024)
    int*    packed  = (int*)(ws + 721056);      // 960000 i
    short*  bfragsG = (short*)(ws + 1681056);   // 1024 s
    float*  out     = (float*)d_out;

    setup_hist<<<RBLK, 512, 0, stream>>>(w2, bfragsG, degi, dst, cntbase);
    conv_fused<<<N_NODES, 256, 0, stream>>>(x, w1, b1, b2, bfragsG, dst, degi, h0);
    scan2_kernel<<<1, 1024, 0, stream>>>(cntbase, binstart, degi, dinv);
    reorder_kernel<<<RBLK, 512, 0, stream>>>(src, dst, cntbase, packed);
    agg1_kernel<<<NBIN, 256, 0, stream>>>(binstart, packed, h0, dinv,
                                          g1w, g1b, g2w, t2p4);
    agg2_kernel<<<NBIN, 256, 0, stream>>>(binstart, packed, t2p4, dinv, g2b, out);
}

// Round 10
// 228.521 us; speedup vs baseline: 2.3494x; 1.3068x over previous
//
#include <hip/hip_runtime.h>
#include <hip/hip_bf16.h>

#define N_NODES 30000
#define F_INLEN 500
#define HID 16
#define OUTC 3
#define NEDGE 960000
#define YPITCH 20               // shorts per row: 40B -> conflict-free, 8B aligned
#define NBIN 938                // bins of 32 nodes: 938*32 = 30016 >= 30000
#define HBLK 128                // hist/reorder blocks
#define EPRH (NEDGE / HBLK)     // 7500 edges per hist/reorder block
#define ECAP 1536               // per-bin edge capacity (mean 1024, max ~1170)
#define NPB2 235                // dinv nodes per reorder block: 128*235 = 30080

typedef float  f32x4 __attribute__((ext_vector_type(4)));
typedef float  f32x2 __attribute__((ext_vector_type(2)));
typedef short  s16x8 __attribute__((ext_vector_type(8)));

static __device__ __forceinline__ unsigned short f2bf(float f) {
    unsigned int u = __float_as_uint(f);
    unsigned int r = (u + 0x7fffu + ((u >> 16) & 1u)) >> 16;
    return (unsigned short)r;
}
static __device__ __forceinline__ unsigned int pack_bf16x2(float v0, float v1) {
#if __has_builtin(__builtin_amdgcn_cvt_pk_bf16_f32)
    typedef __bf16 bf16x2_t __attribute__((ext_vector_type(2)));
    union { bf16x2_t v; unsigned int u; } cv;
    cv.v = __builtin_amdgcn_cvt_pk_bf16_f32(v0, v1);
    return cv.u;
#else
    // single v_perm_b32: truncate both to bf16 (hi16), v1 in high half
    return __builtin_amdgcn_perm(__float_as_uint(v1), __float_as_uint(v0), 0x07060302);
#endif
}

// ---------------- K0: B-fragments + zero degi --------------------------------
__global__ void setup_kernel(const float* __restrict__ w2, short* __restrict__ bfragsG,
                             int* __restrict__ degi)
{
    const int tid = threadIdx.x;
    const int gid = blockIdx.x * 256 + tid;
    if (gid < N_NODES) degi[gid] = 0;
    if (blockIdx.x == 0 && tid < 64) {
        const int n16 = tid & 15, q = tid >> 4;
#pragma unroll
        for (int j = 0; j < 8; j++) {
            {   // s = 0
                const int c = q * 8 + j;
                const int t = c >> 4, i = c & 15;
                bfragsG[tid * 16 + j] = (short)f2bf(w2[n16 * 48 + i * 3 + t]);
            }
            {   // s = 1 (zero for c >= 48)
                const int c = 32 + q * 8 + j;
                short v = 0;
                if (c < 48) { const int t = c >> 4, i = c & 15; v = (short)f2bf(w2[n16 * 48 + i * 3 + t]); }
                bfragsG[tid * 16 + 8 + j] = v;
            }
        }
    }
}

// ---------------- K1: [blocks 0..127] hist+degi  [128..30127] conv -----------
__global__ __launch_bounds__(256, 7) void conv_hist(
    const float* __restrict__ x,
    const float* __restrict__ w1, const float* __restrict__ b1,
    const float* __restrict__ b2, const short* __restrict__ bfragsG,
    const int* __restrict__ dst, int* __restrict__ degi,
    int* __restrict__ cntbase, float* __restrict__ h0)
{
    __shared__ __align__(16) float xp[502];
    __shared__ __align__(16) unsigned short yh[516 * YPITCH];
    __shared__ float red[64];

    const int tid = threadIdx.x;

    // ---- prefix blocks: bin histogram + per-node degree (overlapped w/ conv) ----
    if (blockIdx.x < HBLK) {
        int* histH = (int*)yh;   // alias: 938 ints < yh size
        for (int i = tid; i < NBIN; i += 256) histH[i] = 0;
        __syncthreads();
        const int e0 = blockIdx.x * EPRH;
        for (int e = e0 + tid; e < e0 + EPRH; e += 256) {
            const int d = dst[e];
            atomicAdd(&histH[d >> 5], 1);
            atomicAdd(&degi[d], 1);
        }
        __syncthreads();
        for (int i = tid; i < NBIN; i += 256) cntbase[i * HBLK + blockIdx.x] = histH[i];
        return;
    }

    const int node = blockIdx.x - HBLK;
    const int lane = tid & 63;
    const int wave = tid >> 6;
    const int n16  = lane & 15;
    const int q    = lane >> 4;

    if (tid == 0) { xp[0] = 0.f; xp[501] = 0.f; }
    if (tid < 125) {
        const float4 v = ((const float4*)(x + (long long)node * F_INLEN))[tid];
        xp[4 * tid + 1] = v.x; xp[4 * tid + 2] = v.y;
        xp[4 * tid + 3] = v.z; xp[4 * tid + 4] = v.w;
    }
    {
        const int ri = tid >> 4;
        const int row = (ri == 0) ? 0 : (500 + ri);
        yh[row * YPITCH + (tid & 15)] = 0;
    }
    const s16x8* bfp = (const s16x8*)(bfragsG + lane * 16);
    const s16x8 bh0 = bfp[0], bh1 = bfp[1];

    f32x2 wt0[8], wt1[8], wt2[8], bb[8];
#pragma unroll
    for (int cp = 0; cp < 8; cp++) {
        const int c0 = 2 * cp, c1 = 2 * cp + 1;
        wt0[cp] = (f32x2){w1[c0 * 3 + 0], w1[c1 * 3 + 0]};
        wt1[cp] = (f32x2){w1[c0 * 3 + 1], w1[c1 * 3 + 1]};
        wt2[cp] = (f32x2){w1[c0 * 3 + 2], w1[c1 * 3 + 2]};
        bb[cp]  = (f32x2){b1[c0], b1[c1]};
    }
    __syncthreads();

    // phase 1: conv1 + relu -> bf16, position-major
    for (int p = tid; p < 500; p += 256) {
        const float x0 = xp[p], x1 = xp[p + 1], x2 = xp[p + 2];
        const f32x2 xv0 = {x0, x0}, xv1 = {x1, x1}, xv2 = {x2, x2};
        const f32x2 zero = {0.f, 0.f};
        unsigned int hp[8];
#pragma unroll
        for (int cp = 0; cp < 8; cp++) {
            f32x2 a = bb[cp];
            a = __builtin_elementwise_fma(wt0[cp], xv0, a);
            a = __builtin_elementwise_fma(wt1[cp], xv1, a);
            a = __builtin_elementwise_fma(wt2[cp], xv2, a);
            a = __builtin_elementwise_max(a, zero);
            hp[cp] = pack_bf16x2(a[0], a[1]);
        }
        uint2* d = (uint2*)&yh[(p + 1) * YPITCH];
        d[0] = make_uint2(hp[0], hp[1]);
        d[1] = make_uint2(hp[2], hp[3]);
        d[2] = make_uint2(hp[4], hp[5]);
        d[3] = make_uint2(hp[6], hp[7]);
    }
    __syncthreads();

    // phase 2: MFMA over 32 M-tiles; masks only on tile 31
    struct S8 { short4 lo, hi; };
    float mx0 = -3.0e38f, mx1 = -3.0e38f, mx2 = -3.0e38f, mx3 = -3.0e38f;
#pragma unroll
    for (int it = 0; it < 8; it++) {
        const int tile = wave * 8 + it;
        const int p0 = tile * 16 + n16;
        const int cA = (q & 1) * 8;
        const int rA = p0 + (q >> 1);
        const int rB = p0 + 2 + (q >> 1);
        S8 t0, t1;
        t0.lo = *(const short4*)&yh[rA * YPITCH + cA];
        t0.hi = *(const short4*)&yh[rA * YPITCH + cA + 4];
        t1.lo = *(const short4*)&yh[rB * YPITCH + cA];
        t1.hi = *(const short4*)&yh[rB * YPITCH + cA + 4];
        const s16x8 ah0 = *(const s16x8*)&t0;
        const s16x8 ah1 = *(const s16x8*)&t1;
        f32x4 acc = {0.f, 0.f, 0.f, 0.f};
        acc = __builtin_amdgcn_mfma_f32_16x16x32_bf16(ah0, bh0, acc, 0, 0, 0);
        acc = __builtin_amdgcn_mfma_f32_16x16x32_bf16(ah1, bh1, acc, 0, 0, 0);
        if (it < 7) {   // tiles 0..30 for waves 0..3 at it<7 are all-valid... (tile<=30)
            mx0 = fmaxf(mx0, acc[0]);
            mx1 = fmaxf(mx1, acc[1]);
            mx2 = fmaxf(mx2, acc[2]);
            mx3 = fmaxf(mx3, acc[3]);
        } else if (wave < 3) {   // tiles 7,15,23: all-valid
            mx0 = fmaxf(mx0, acc[0]);
            mx1 = fmaxf(mx1, acc[1]);
            mx2 = fmaxf(mx2, acc[2]);
            mx3 = fmaxf(mx3, acc[3]);
        } else if (q == 0) {     // tile 31: rows 496..499 valid only (q==0)
            mx0 = fmaxf(mx0, acc[0]);
            mx1 = fmaxf(mx1, acc[1]);
            mx2 = fmaxf(mx2, acc[2]);
            mx3 = fmaxf(mx3, acc[3]);
        }
    }
    float m = fmaxf(fmaxf(mx0, mx1), fmaxf(mx2, mx3));
    m = fmaxf(m, __shfl_xor(m, 16));
    m = fmaxf(m, __shfl_xor(m, 32));
    if (lane < 16) red[wave * 16 + lane] = m;
    __syncthreads();
    if (tid < 16) {
        const float mm = fmaxf(fmaxf(red[tid], red[16 + tid]), fmaxf(red[32 + tid], red[48 + tid]));
        h0[node * HID + tid] = fmaxf(mm + b2[tid], 0.f);
    }
}

// ---------------- K2: reorder w/ integrated scan + dinv ----------------------
// 128 blocks x 512 thr, 7500 edges each; every block recomputes the global scan.
__global__ __launch_bounds__(512) void reorder2(
    const int* __restrict__ src, const int* __restrict__ dst,
    const int* __restrict__ cntbase, int* __restrict__ packed,
    int* __restrict__ binstart, const int* __restrict__ degi,
    float* __restrict__ dinv)
{
    __shared__ int scA[NBIN], scB[NBIN];
    __shared__ int gexc[NBIN];    // binstart[bin] + psum(this block) -> global base
    __shared__ int lexc[NBIN];    // local exclusive offset
    __shared__ int cursor[NBIN];  // scatter cursor
    __shared__ int srt[EPRH];
    __shared__ unsigned short sbin[EPRH];
    const int tid = threadIdx.x;
    const int blk = blockIdx.x;

    // A: per-bin reduce over blocks + psum(<blk) + own count
    const int kblk = blk >> 2, rem = blk & 3;
    for (int bin = tid; bin < NBIN; bin += 512) {
        const int4* row = (const int4*)(cntbase + bin * HBLK);
        int tot = 0, psum = 0, lc = 0;
        for (int k = 0; k < kblk; k++) {
            const int4 v = row[k];
            const int s4 = v.x + v.y + v.z + v.w;
            tot += s4; psum += s4;
        }
        {
            const int4 v = row[kblk];
            tot += v.x + v.y + v.z + v.w;
            if (rem > 0) psum += v.x;
            if (rem > 1) psum += v.y;
            if (rem > 2) psum += v.z;
            lc = (rem == 0) ? v.x : (rem == 1) ? v.y : (rem == 2) ? v.z : v.w;
        }
        for (int k = kblk + 1; k < HBLK / 4; k++) {
            const int4 v = row[k];
            tot += v.x + v.y + v.z + v.w;
        }
        cursor[bin] = tot;    // temp: tot
        gexc[bin]   = psum;   // temp: psum
        lexc[bin]   = lc;     // temp: own count
        scA[bin]    = tot;
    }
    __syncthreads();
    // scan 1: inclusive Hillis-Steele over tot (10 rounds -> ends in scA)
    {
        int* pA = scA; int* pB = scB;
        for (int off = 1; off < NBIN; off <<= 1) {
            for (int i = tid; i < NBIN; i += 512)
                pB[i] = pA[i] + ((i >= off) ? pA[i - off] : 0);
            __syncthreads();
            int* tp = pA; pA = pB; pB = tp;
        }
        for (int i = tid; i < NBIN; i += 512) {
            const int excl = pA[i] - cursor[i];   // binstart[i]
            gexc[i] += excl;
            if (blk == 0) binstart[i] = excl;
        }
        if (blk == 0 && tid == 0) binstart[NBIN] = NEDGE;
    }
    __syncthreads();
    // scan 2: local exclusive over own counts
    for (int i = tid; i < NBIN; i += 512) scA[i] = lexc[i];
    __syncthreads();
    {
        int* pA = scA; int* pB = scB;
        for (int off = 1; off < NBIN; off <<= 1) {
            for (int i = tid; i < NBIN; i += 512)
                pB[i] = pA[i] + ((i >= off) ? pA[i - off] : 0);
            __syncthreads();
            int* tp = pA; pA = pB; pB = tp;
        }
        for (int i = tid; i < NBIN; i += 512) {
            const int e2 = pA[i] - lexc[i];
            lexc[i] = e2;
            cursor[i] = e2;
        }
    }
    __syncthreads();
    // B: LDS counting-sort scatter
    const int e0 = blk * EPRH;
    for (int e = e0 + tid; e < e0 + EPRH; e += 512) {
        const int d = dst[e];
        const int bin = d >> 5;
        const int pos = atomicAdd(&cursor[bin], 1);
        srt[pos] = src[e] | ((d & 31) << 16);
        sbin[pos] = (unsigned short)bin;
    }
    __syncthreads();
    // C: bin-sorted writeout (runs of ~8 -> coalesced-ish)
    for (int i = tid; i < EPRH; i += 512) {
        const int bin = sbin[i];
        packed[gexc[bin] + (i - lexc[bin])] = srt[i];
    }
    // D: dinv slice
    const int n0 = blk * NPB2;
    for (int n = n0 + tid; n < n0 + NPB2 && n < N_NODES; n += 512)
        dinv[n] = rsqrtf((float)(degi[n] + 1));
}

// ---------------- K3: agg layer 1: sort-by-dloc + register segmented sum -----
__global__ __launch_bounds__(256) void agg1_kernel(
    const int* __restrict__ binstart, const int* __restrict__ packed,
    const float* __restrict__ h0, const float* __restrict__ dinv,
    const float* __restrict__ W1, const float* __restrict__ b1g,
    const float* __restrict__ W2, float4* __restrict__ t2p4)
{
    __shared__ float w1s[256];
    __shared__ float w2s[48];
    __shared__ float b1s[16];
    __shared__ float accS[32 * 17];
    __shared__ int eL[ECAP];
    __shared__ int srt[ECAP];
    __shared__ int h32[32], ls32[32], lofs32[32];
    const int tid = threadIdx.x;
    const int blk = blockIdx.x;
    w1s[tid] = W1[tid];
    if (tid < 48) w2s[tid] = W2[tid];
    if (tid < 16) b1s[tid] = b1g[tid];
    if (tid < 32) h32[tid] = 0;
    const int beg = binstart[blk];
    const int cnt = binstart[blk + 1] - beg;
    __syncthreads();
    for (int j = tid; j < cnt; j += 256) {
        const int p = packed[beg + j];
        eL[j] = p;
        atomicAdd(&h32[p >> 16], 1);
    }
    __syncthreads();
    if (tid < 32) {
        const int v = h32[tid];
        int inc = v;
#pragma unroll
        for (int off = 1; off < 32; off <<= 1) {
            const int y = __shfl_up(inc, off);
            if (tid >= off) inc += y;
        }
        ls32[tid] = inc - v;
        lofs32[tid] = inc - v;
    }
    __syncthreads();
    for (int j = tid; j < cnt; j += 256) {
        const int p = eL[j];
        const int pos = atomicAdd(&lofs32[p >> 16], 1);
        srt[pos] = p;
    }
    __syncthreads();
    const int n = tid >> 3;
    const int eslot = (tid >> 2) & 1;
    const int q = tid & 3;
    const int node = blk * 32 + n;
    const bool valid = node < N_NODES;
    f32x4 acc = {0.f, 0.f, 0.f, 0.f};
    if (valid) {
        const int s0 = ls32[n];
        const int s1 = s0 + h32[n];
        for (int i = s0 + eslot; i < s1; i += 2) {
            const int s = srt[i] & 0xFFFF;
            const f32x4 v = *(const f32x4*)(h0 + s * HID + q * 4);
            acc += v * dinv[s];
        }
    }
#pragma unroll
    for (int c = 0; c < 4; c++) acc[c] += __shfl_xor(acc[c], 4);
    if (valid && eslot == 0) {
        const f32x4 sf = *(const f32x4*)(h0 + node * HID + q * 4);
        acc += sf * dinv[node];
        accS[n * 17 + q * 4 + 0] = acc[0];
        accS[n * 17 + q * 4 + 1] = acc[1];
        accS[n * 17 + q * 4 + 2] = acc[2];
        accS[n * 17 + q * 4 + 3] = acc[3];
    }
    __syncthreads();
    if (tid < 128) {
        const int n2 = tid >> 2;
        const int node2 = blk * 32 + n2;
        if (node2 < N_NODES) {
            const float dv = dinv[node2];
            const int q2 = tid & 3;
            float y0 = 0.f, y1 = 0.f, y2 = 0.f, y3 = 0.f;
#pragma unroll
            for (int i = 0; i < 16; i++) {
                const float a = accS[n2 * 17 + i];
                y0 = fmaf(a, w1s[i * 16 + q2 * 4 + 0], y0);
                y1 = fmaf(a, w1s[i * 16 + q2 * 4 + 1], y1);
                y2 = fmaf(a, w1s[i * 16 + q2 * 4 + 2], y2);
                y3 = fmaf(a, w1s[i * 16 + q2 * 4 + 3], y3);
            }
            float d0 = 0.f, d1 = 0.f, d2 = 0.f;
            const float yv[4] = {y0, y1, y2, y3};
#pragma unroll
            for (int j = 0; j < 4; j++) {
                const int o = q2 * 4 + j;
                const float h = fmaxf(b1s[o] + dv * yv[j], 0.f);
                d0 = fmaf(h, w2s[o * 3 + 0], d0);
                d1 = fmaf(h, w2s[o * 3 + 1], d1);
                d2 = fmaf(h, w2s[o * 3 + 2], d2);
            }
            d0 += __shfl_xor(d0, 1); d0 += __shfl_xor(d0, 2);
            d1 += __shfl_xor(d1, 1); d1 += __shfl_xor(d1, 2);
            d2 += __shfl_xor(d2, 1); d2 += __shfl_xor(d2, 2);
            if (q2 == 0) t2p4[node2] = make_float4(d0 * dv, d1 * dv, d2 * dv, 0.f);
        }
    }
}

// ---------------- K4: agg layer 2 + bias + log_softmax -----------------------
__global__ __launch_bounds__(256) void agg2_kernel(
    const int* __restrict__ binstart, const int* __restrict__ packed,
    const float4* __restrict__ t2p4, const float* __restrict__ dinv,
    const float* __restrict__ b2g, float* __restrict__ out)
{
    __shared__ int eL[ECAP];
    __shared__ int srt[ECAP];
    __shared__ int h32[32], ls32[32], lofs32[32];
    const int tid = threadIdx.x;
    const int blk = blockIdx.x;
    if (tid < 32) h32[tid] = 0;
    const int beg = binstart[blk];
    const int cnt = binstart[blk + 1] - beg;
    __syncthreads();
    for (int j = tid; j < cnt; j += 256) {
        const int p = packed[beg + j];
        eL[j] = p;
        atomicAdd(&h32[p >> 16], 1);
    }
    __syncthreads();
    if (tid < 32) {
        const int v = h32[tid];
        int inc = v;
#pragma unroll
        for (int off = 1; off < 32; off <<= 1) {
            const int y = __shfl_up(inc, off);
            if (tid >= off) inc += y;
        }
        ls32[tid] = inc - v;
        lofs32[tid] = inc - v;
    }
    __syncthreads();
    for (int j = tid; j < cnt; j += 256) {
        const int p = eL[j];
        const int pos = atomicAdd(&lofs32[p >> 16], 1);
        srt[pos] = p;
    }
    __syncthreads();
    const int n = tid >> 3;
    const int ln8 = tid & 7;
    const int node = blk * 32 + n;
    float a0 = 0.f, a1 = 0.f, a2 = 0.f;
    if (node < N_NODES) {
        const int s0 = ls32[n];
        const int s1 = s0 + h32[n];
        for (int i = s0 + ln8; i < s1; i += 8) {
            const int s = srt[i] & 0xFFFF;
            const float4 v = t2p4[s];
            a0 += v.x; a1 += v.y; a2 += v.z;
        }
    }
#pragma unroll
    for (int msk = 1; msk < 8; msk <<= 1) {
        a0 += __shfl_xor(a0, msk);
        a1 += __shfl_xor(a1, msk);
        a2 += __shfl_xor(a2, msk);
    }
    if (ln8 == 0 && node < N_NODES) {
        const float dv = dinv[node];
        const float4 self = t2p4[node];
        const float z0 = b2g[0] + dv * (a0 + self.x);
        const float z1 = b2g[1] + dv * (a1 + self.y);
        const float z2 = b2g[2] + dv * (a2 + self.z);
        const float m = fmaxf(z0, fmaxf(z1, z2));
        const float lg = m + logf(expf(z0 - m) + expf(z1 - m) + expf(z2 - m));
        out[node * 3 + 0] = z0 - lg;
        out[node * 3 + 1] = z1 - lg;
        out[node * 3 + 2] = z2 - lg;
    }
}

extern "C" void kernel_launch(void* const* d_in, const int* in_sizes, int n_in,
                              void* d_out, int out_size, void* d_ws, size_t ws_size,
                              hipStream_t stream)
{
    const float* x   = (const float*)d_in[0];
    const float* w1  = (const float*)d_in[1];
    const float* b1  = (const float*)d_in[2];
    const float* w2  = (const float*)d_in[3];
    const float* b2  = (const float*)d_in[4];
    const float* g1w = (const float*)d_in[5];
    const float* g1b = (const float*)d_in[6];
    const float* g2w = (const float*)d_in[7];
    const float* g2b = (const float*)d_in[8];
    const int*   ei  = (const int*)d_in[9];
    const int* src = ei;
    const int* dst = ei + NEDGE;

    float* ws = (float*)d_ws;
    float*  h0      = ws;                       // 480000 f
    float*  dinv    = ws + 480000;              // 30000 f
    float4* t2p4    = (float4*)(ws + 510000);   // 30000 float4 (16B aligned)
    int*    degi    = (int*)(ws + 630000);      // 30000 i
    int*    cntbase = (int*)(ws + 660000);      // 938*128 = 120064 i (16B aligned)
    int*    binstart= (int*)(ws + 780064);      // 939 (+pad)
    int*    packed  = (int*)(ws + 781024);      // 960000 i
    short*  bfragsG = (short*)(ws + 1741024);   // 1024 s
    float*  out     = (float*)d_out;

    setup_kernel<<<118, 256, 0, stream>>>(w2, bfragsG, degi);
    conv_hist<<<HBLK + N_NODES, 256, 0, stream>>>(x, w1, b1, b2, bfragsG,
                                                  dst, degi, cntbase, h0);
    reorder2<<<HBLK, 512, 0, stream>>>(src, dst, cntbase, packed, binstart, degi, dinv);
    agg1_kernel<<<NBIN, 256, 0, stream>>>(binstart, packed, h0, dinv,
                                          g1w, g1b, g2w, t2p4);
    agg2_kernel<<<NBIN, 256, 0, stream>>>(binstart, packed, t2p4, dinv, g2b, out);
}